// Round 9
// baseline (263.460 us; speedup 1.0000x reference)
//
#include <hip/hip_runtime.h>

// GCN layer: out = ReLU(BN(GCNConv(x) + x@skip_W))
// R9: build-chain consolidation — scan_bases fused into scan_buckets
//     (last-block-done pattern), prep fused into hist, int4 edge reads,
//     shfl-based scans. fp8 gather + hoisted bf16 MFMA GEMM (R8).

typedef unsigned short ushort;
typedef __bf16 bf16x8 __attribute__((ext_vector_type(8)));
typedef float f32x4 __attribute__((ext_vector_type(4)));
typedef float f32x2 __attribute__((ext_vector_type(2)));

constexpr int N_NODES = 100000;
constexpr int N_PAD   = 100096;                  // 782*128
constexpr int E_EDGES = 1600000;

constexpr int BUCK_SHIFT = 7;                    // 128 nodes per bucket
constexpr int NBUCK   = (N_NODES + 127) / 128;   // 782
constexpr int NBUCK_P = 784;
constexpr int CHUNK   = 4096;
constexpr int NCHUNK  = (E_EDGES + CHUNK - 1) / CHUNK;  // 391
constexpr int SORT_CAP = 4096;

// ws layout (4-byte element offsets)
constexpr size_t OFF_SCALE  = 0;         // 256 floats (scale/shift)
constexpr size_t OFF_DINV   = 256;       // N_PAD floats
constexpr size_t OFF_ROWPTR = 100352;    // N+1 ints
constexpr size_t OFF_BASE   = 200480;    // NBUCK+1 ints (pad 800)
constexpr size_t OFF_DONE   = 201272;    // 2 ints (zeroed by memset)
constexpr size_t OFF_GHIST  = 201280;    // NCHUNK*NBUCK_P = 306544 ints
constexpr size_t OFF_PART   = OFF_GHIST; // 782*256 floats, aliases gh (dead post-scatter)
constexpr size_t OFF_BINNED = 507824;    // E ints (packed edges; csr in place)
constexpr size_t OFF_XB     = 2107824;   // N_PAD*64 ushort
constexpr size_t OFF_U      = 5310896;   // N_PAD*64 ushort
constexpr size_t OFF_PRE    = 8513968;   // N_PAD*128 ushort (bf16 pre-BN)
constexpr size_t OFF_XD8    = OFF_PRE;   // N_PAD*16 uints, aliases pre (dead by k_gemm)
constexpr size_t OFF_BT     = 14920112;  // 128*128 ushort

static __device__ __forceinline__ ushort f2bf(float f) {
    union { float f; unsigned u; } v; v.f = f;
    unsigned r = v.u + 0x7FFFu + ((v.u >> 16) & 1u);  // RNE
    return (ushort)(r >> 16);
}
static __device__ __forceinline__ float bf2f(ushort u) {
    union { unsigned u; float f; } v; v.u = (unsigned)u << 16;
    return v.f;
}
static __device__ __forceinline__ unsigned pack_fp8x4(float a, float b, float c, float d) {
    int r = 0;
    r = __builtin_amdgcn_cvt_pk_fp8_f32(a, b, r, false);
    r = __builtin_amdgcn_cvt_pk_fp8_f32(c, d, r, true);
    return (unsigned)r;
}

// ---- hist (blocks 0..NCHUNK-1) + Bt prep (blocks NCHUNK..NCHUNK+63) ----
__global__ __launch_bounds__(256) void k_hist(const int* __restrict__ col,
                                              int* __restrict__ gh,
                                              const float* __restrict__ W,
                                              const float* __restrict__ skipW,
                                              ushort* __restrict__ Bt) {
    int c = blockIdx.x, t = threadIdx.x;
    if (c >= NCHUNK) {  // prep: Bt[n][k] = bf16(B[k][n])
        int idx = (c - NCHUNK) * 256 + t;
        int k = idx >> 7, n = idx & 127;
        float v = (k < 64) ? W[k * 128 + n] : skipW[(k - 64) * 128 + n];
        Bt[n * 128 + k] = f2bf(v);
        return;
    }
    __shared__ int h[NBUCK_P];
    for (int b = t; b < NBUCK_P; b += 256) h[b] = 0;
    __syncthreads();
    const int4* col4 = (const int4*)col;
    int g0 = c * (CHUNK / 4);
#pragma unroll
    for (int i = 0; i < CHUNK / 1024; ++i) {
        int g4 = g0 + i * 256 + t;
        if (g4 * 4 + 3 < E_EDGES) {
            int4 cc = col4[g4];
            atomicAdd(&h[cc.x >> BUCK_SHIFT], 1);
            atomicAdd(&h[cc.y >> BUCK_SHIFT], 1);
            atomicAdd(&h[cc.z >> BUCK_SHIFT], 1);
            atomicAdd(&h[cc.w >> BUCK_SHIFT], 1);
        } else {
#pragma unroll
            for (int j = 0; j < 4; ++j) {
                int e = g4 * 4 + j;
                if (e < E_EDGES) atomicAdd(&h[col[e] >> BUCK_SHIFT], 1);
            }
        }
    }
    __syncthreads();
    for (int b = t; b < NBUCK_P; b += 256) gh[c * NBUCK_P + b] = h[b];
}

// ---- per-bucket scan over chunks + fused bucket-base scan (last block) ----
__global__ __launch_bounds__(512) void k_scan_buckets(int* __restrict__ gh,
                                                      int* __restrict__ base,
                                                      int* __restrict__ rowptr,
                                                      int* __restrict__ done) {
    __shared__ int lds[1024];
    __shared__ int lastflag;
    int b = blockIdx.x, t = threadIdx.x;
    int v = (t < NCHUNK) ? gh[t * NBUCK_P + b] : 0;
    lds[t] = v;
    __syncthreads();
    int val = v;
#pragma unroll
    for (int off = 1; off < 512; off <<= 1) {
        int add = (t >= off) ? lds[t - off] : 0;
        __syncthreads();
        val += add;
        lds[t] = val;
        __syncthreads();
    }
    if (t < NCHUNK) gh[t * NBUCK_P + b] = val - v;  // exclusive within bucket
    if (t == 511) {
        __hip_atomic_store(&base[b], val, __ATOMIC_RELEASE, __HIP_MEMORY_SCOPE_AGENT);
        int old = __hip_atomic_fetch_add(done, 1, __ATOMIC_ACQ_REL, __HIP_MEMORY_SCOPE_AGENT);
        lastflag = (old == NBUCK - 1) ? 1 : 0;
    }
    __syncthreads();
    if (!lastflag) return;

    // last block: exclusive scan of 782 bucket totals (1024-slot ladder)
    int v0 = (t < NBUCK) ? __hip_atomic_load(&base[t], __ATOMIC_ACQUIRE, __HIP_MEMORY_SCOPE_AGENT) : 0;
    int v1 = (512 + t < NBUCK) ? __hip_atomic_load(&base[512 + t], __ATOMIC_ACQUIRE, __HIP_MEMORY_SCOPE_AGENT) : 0;
    __syncthreads();   // ladder reused lds
    lds[t] = v0;
    lds[512 + t] = v1;
    __syncthreads();
#pragma unroll
    for (int off = 1; off < 1024; off <<= 1) {
        int a0 = (t >= off) ? lds[t - off] : 0;
        int a1 = (512 + t >= off) ? lds[512 + t - off] : 0;
        __syncthreads();
        lds[t] += a0;
        lds[512 + t] += a1;
        __syncthreads();
    }
    if (t < NBUCK) base[t] = lds[t] - v0;
    if (512 + t < NBUCK) base[512 + t] = lds[512 + t] - v1;
    if (t == 511) {
        int total = lds[1023];
        base[NBUCK] = total;
        rowptr[N_NODES] = total;
    }
}

// ---- scatter edges into bucket-contiguous array (packed), int4 reads ----
__global__ __launch_bounds__(256) void k_scatter_bin(const int* __restrict__ row,
                                                     const int* __restrict__ col,
                                                     const int* __restrict__ gh,
                                                     const int* __restrict__ base,
                                                     unsigned int* __restrict__ binned) {
    __shared__ int cur[NBUCK_P];
    int c = blockIdx.x, t = threadIdx.x;
    for (int b = t; b < NBUCK_P; b += 256) {
        int bb = (b < NBUCK) ? base[b] : 0;
        cur[b] = bb + gh[c * NBUCK_P + b];
    }
    __syncthreads();
    const int4* col4 = (const int4*)col;
    const int4* row4 = (const int4*)row;
    int g0 = c * (CHUNK / 4);
#pragma unroll
    for (int i = 0; i < CHUNK / 1024; ++i) {
        int g4 = g0 + i * 256 + t;
        if (g4 * 4 + 3 < E_EDGES) {
            int4 cc = col4[g4];
            int4 rr = row4[g4];
            int p;
            p = atomicAdd(&cur[cc.x >> BUCK_SHIFT], 1);
            binned[p] = ((unsigned)(cc.x & 127) << 17) | (unsigned)rr.x;
            p = atomicAdd(&cur[cc.y >> BUCK_SHIFT], 1);
            binned[p] = ((unsigned)(cc.y & 127) << 17) | (unsigned)rr.y;
            p = atomicAdd(&cur[cc.z >> BUCK_SHIFT], 1);
            binned[p] = ((unsigned)(cc.z & 127) << 17) | (unsigned)rr.z;
            p = atomicAdd(&cur[cc.w >> BUCK_SHIFT], 1);
            binned[p] = ((unsigned)(cc.w & 127) << 17) | (unsigned)rr.w;
        } else {
#pragma unroll
            for (int j = 0; j < 4; ++j) {
                int e = g4 * 4 + j;
                if (e < E_EDGES) {
                    int d = col[e], s = row[e];
                    int p = atomicAdd(&cur[d >> BUCK_SHIFT], 1);
                    binned[p] = ((unsigned)(d & 127) << 17) | (unsigned)s;
                }
            }
        }
    }
}

// ---- per-bucket counting sort (shfl scan) -> csr, rowptr, dinv; fused cast ----
__global__ __launch_bounds__(256) void k_sortbucket(unsigned int* __restrict__ binned,
                                                    const int* __restrict__ base,
                                                    int* __restrict__ rowptr,
                                                    float* __restrict__ dinv,
                                                    const float* __restrict__ x,
                                                    ushort* __restrict__ xb,
                                                    unsigned* __restrict__ xd8) {
    __shared__ unsigned int ebuf[SORT_CAP];
    __shared__ int sbuf[SORT_CAP];
    __shared__ int lcnt[128];
    __shared__ int lptr[128];
    __shared__ float ldinv[128];
    __shared__ int wsum[2];
    int b = blockIdx.x, t = threadIdx.x;
    int i0 = base[b], i1 = base[b + 1];
    int cnt = i1 - i0;
    if (cnt > SORT_CAP) cnt = SORT_CAP;
    int n0 = b << BUCK_SHIFT;
    int nn = min(128, N_NODES - n0);

    for (int k = t; k < cnt; k += 256) ebuf[k] = binned[i0 + k];
    if (t < 128) lcnt[t] = 0;
    __syncthreads();
    for (int k = t; k < cnt; k += 256) atomicAdd(&lcnt[ebuf[k] >> 17], 1);
    __syncthreads();

    // 128-wide exclusive scan via 2-wave shfl
    int myc = 0, val = 0;
    if (t < 128) {
        myc = lcnt[t];
        val = myc;
#pragma unroll
        for (int d = 1; d < 64; d <<= 1) {
            int o = __shfl_up(val, d);
            if ((t & 63) >= d) val += o;
        }
        if ((t & 63) == 63) wsum[t >> 6] = val;
    }
    __syncthreads();
    if (t < 128) {
        if (t >= 64) val += wsum[0];
        int excl = val - myc;
        lptr[t] = excl;
        float dv = rsqrtf((float)myc + 1.0f);  // +1 self loop
        ldinv[t] = dv;
        if (t < nn) {
            rowptr[n0 + t] = i0 + excl;
            dinv[n0 + t] = dv;
        }
    }
    __syncthreads();
    for (int k = t; k < cnt; k += 256) {
        unsigned int e = ebuf[k];
        int j = (int)(e >> 17);
        int p = atomicAdd(&lptr[j], 1);
        sbuf[p] = (int)(e & 0x1FFFF);
    }
    __syncthreads();
    for (int k = t; k < cnt; k += 256) binned[i0 + k] = (unsigned int)sbuf[k];

    // fused cast: this bucket's 128 node rows -> xb (bf16), xd8 (fp8*dinv)
#pragma unroll
    for (int it = 0; it < 8; ++it) {
        int idx = it * 256 + t;          // 0..2047
        int nl = idx >> 4, q = idx & 15;
        int c = n0 + nl;
        ushort4 bb = {0, 0, 0, 0};
        unsigned w8 = 0;
        if (nl < nn) {
            float4 v = ((const float4*)x)[(size_t)c * 16 + q];
            bb.x = f2bf(v.x); bb.y = f2bf(v.y); bb.z = f2bf(v.z); bb.w = f2bf(v.w);
            float d = ldinv[nl];
            w8 = pack_fp8x4(v.x * d, v.y * d, v.z * d, v.w * d);
        }
        ((ushort4*)xb)[(size_t)c * 16 + q] = bb;
        xd8[(size_t)c * 16 + q] = w8;
    }
}

// ---- aggregation: 16 lanes per node; fp8 gather (1 line/edge), unroll-8 ----
__global__ __launch_bounds__(256) void k_agg(const unsigned* __restrict__ xd8,
                                             const float* __restrict__ dinv,
                                             const int* __restrict__ rowptr,
                                             const unsigned int* __restrict__ csr,
                                             ushort* __restrict__ u) {
    int t = blockIdx.x * blockDim.x + threadIdx.x;
    if (t >= N_PAD * 16) return;
    int c = t >> 4;
    int q = t & 15;
    if (c >= N_NODES) {
        ushort4 z = {0, 0, 0, 0};
        ((ushort4*)u)[t] = z;
        return;
    }
    float dc = dinv[c];
    float4 acc;
    {
        unsigned w = xd8[t];
        f32x2 lo = __builtin_amdgcn_cvt_pk_f32_fp8((int)w, false);
        f32x2 hi = __builtin_amdgcn_cvt_pk_f32_fp8((int)w, true);
        acc.x = lo.x; acc.y = lo.y; acc.z = hi.x; acc.w = hi.y;
    }
    int i0 = rowptr[c], i1 = rowptr[c + 1];
    int i = i0;
    for (; i + 8 <= i1; i += 8) {
        int s[8];
#pragma unroll
        for (int k = 0; k < 8; ++k) s[k] = (int)csr[i + k];
        unsigned w[8];
#pragma unroll
        for (int k = 0; k < 8; ++k) w[k] = xd8[s[k] * 16 + q];
#pragma unroll
        for (int k = 0; k < 8; ++k) {
            f32x2 lo = __builtin_amdgcn_cvt_pk_f32_fp8((int)w[k], false);
            f32x2 hi = __builtin_amdgcn_cvt_pk_f32_fp8((int)w[k], true);
            acc.x += lo.x; acc.y += lo.y; acc.z += hi.x; acc.w += hi.y;
        }
    }
    for (; i < i1; ++i) {
        unsigned w = xd8[(int)csr[i] * 16 + q];
        f32x2 lo = __builtin_amdgcn_cvt_pk_f32_fp8((int)w, false);
        f32x2 hi = __builtin_amdgcn_cvt_pk_f32_fp8((int)w, true);
        acc.x += lo.x; acc.y += lo.y; acc.z += hi.x; acc.w += hi.y;
    }
    ushort4 o;
    o.x = f2bf(acc.x * dc); o.y = f2bf(acc.y * dc);
    o.z = f2bf(acc.z * dc); o.w = f2bf(acc.w * dc);
    ((ushort4*)u)[t] = o;
}

// ---- MFMA GEMM: pre = [u|xb] @ Bt^T + bias (bf16 out); per-block partials ----
__global__ __launch_bounds__(256) void k_gemm(const ushort* __restrict__ u,
                                              const ushort* __restrict__ xb,
                                              const ushort* __restrict__ Bt,
                                              const float* __restrict__ bias,
                                              ushort* __restrict__ pre,
                                              float* __restrict__ partial) {
    __shared__ float sred[128];
    __shared__ float qred[128];
    int tid = threadIdx.x;
    int wave = tid >> 6, lane = tid & 63;
    int wm = wave >> 1, wn = wave & 1;
    int l15 = lane & 15, quad = lane >> 4;
    int row0 = blockIdx.x * 128 + wm * 64;
    int col0 = wn * 64;

    if (tid < 128) { sred[tid] = 0.f; qred[tid] = 0.f; }
    __syncthreads();

    bf16x8 af[4][4], bf_[4][4];
#pragma unroll
    for (int kc = 0; kc < 4; ++kc) {
        const ushort* abase = (kc < 2) ? u : xb;
        int ko = (kc & 1) * 32 + quad * 8;
#pragma unroll
        for (int im = 0; im < 4; ++im)
            af[kc][im] = *(const bf16x8*)&abase[(size_t)(row0 + im * 16 + l15) * 64 + ko];
#pragma unroll
        for (int jn = 0; jn < 4; ++jn)
            bf_[kc][jn] = *(const bf16x8*)&Bt[(size_t)(col0 + jn * 16 + l15) * 128 + kc * 32 + quad * 8];
    }

    f32x4 acc[4][4];
#pragma unroll
    for (int a = 0; a < 4; ++a)
#pragma unroll
        for (int b = 0; b < 4; ++b) acc[a][b] = (f32x4){0.f, 0.f, 0.f, 0.f};

#pragma unroll
    for (int kc = 0; kc < 4; ++kc)
#pragma unroll
        for (int im = 0; im < 4; ++im)
#pragma unroll
            for (int jn = 0; jn < 4; ++jn)
                acc[im][jn] = __builtin_amdgcn_mfma_f32_16x16x32_bf16(
                    af[kc][im], bf_[kc][jn], acc[im][jn], 0, 0, 0);

    int coln[4];
    float bi[4];
#pragma unroll
    for (int jn = 0; jn < 4; ++jn) {
        coln[jn] = col0 + jn * 16 + l15;
        bi[jn] = bias[coln[jn]];
    }
    float lsum[4] = {0.f, 0.f, 0.f, 0.f};
    float lsq[4]  = {0.f, 0.f, 0.f, 0.f};
#pragma unroll
    for (int im = 0; im < 4; ++im) {
        int rbase = row0 + im * 16 + quad * 4;
#pragma unroll
        for (int r = 0; r < 4; ++r) {
            int rowi = rbase + r;
            if (rowi < N_NODES) {
#pragma unroll
                for (int jn = 0; jn < 4; ++jn) {
                    float v = acc[im][jn][r] + bi[jn];
                    pre[(size_t)rowi * 128 + coln[jn]] = f2bf(v);
                    lsum[jn] += v;
                    lsq[jn]  += v * v;
                }
            }
        }
    }
#pragma unroll
    for (int jn = 0; jn < 4; ++jn) {
        atomicAdd(&sred[coln[jn]], lsum[jn]);
        atomicAdd(&qred[coln[jn]], lsq[jn]);
    }
    __syncthreads();
    if (tid < 128) {
        partial[(size_t)blockIdx.x * 256 + tid]       = sred[tid];
        partial[(size_t)blockIdx.x * 256 + 128 + tid] = qred[tid];
    }
}

// ---- reduce 782 partials -> scale/shift (one block per output column) ----
__global__ __launch_bounds__(256) void k_reduce(const float* __restrict__ partial,
                                                const float* __restrict__ gamma,
                                                const float* __restrict__ beta,
                                                float* __restrict__ scaleshift) {
    __shared__ float ls[256], lq[256];
    int j = blockIdx.x;   // 0..127
    int t = threadIdx.x;
    float s = 0.f, q = 0.f;
    for (int p = t; p < NBUCK; p += 256) {
        s += partial[(size_t)p * 256 + j];
        q += partial[(size_t)p * 256 + 128 + j];
    }
    ls[t] = s; lq[t] = q;
    __syncthreads();
#pragma unroll
    for (int off = 128; off > 0; off >>= 1) {
        if (t < off) { ls[t] += ls[t + off]; lq[t] += lq[t + off]; }
        __syncthreads();
    }
    if (t == 0) {
        float mean = ls[0] * (1.0f / N_NODES);
        float var  = lq[0] * (1.0f / N_NODES) - mean * mean;
        float sc   = gamma[j] * rsqrtf(var + 1e-5f);
        scaleshift[j]       = sc;
        scaleshift[128 + j] = beta[j] - mean * sc;
    }
}

// read bf16 pre, write fp32 out
__global__ void k_apply(const ushort* __restrict__ pre, float* __restrict__ out,
                        const float* __restrict__ scaleshift) {
    int t = blockIdx.x * blockDim.x + threadIdx.x;
    if (t >= N_NODES * 32) return;
    int j4 = t & 31;
    ushort4 p = ((const ushort4*)pre)[t];
    float4 sc = ((const float4*)scaleshift)[j4];
    float4 sh = ((const float4*)(scaleshift + 128))[j4];
    float4 v;
    v.x = fmaxf(fmaf(bf2f(p.x), sc.x, sh.x), 0.f);
    v.y = fmaxf(fmaf(bf2f(p.y), sc.y, sh.y), 0.f);
    v.z = fmaxf(fmaf(bf2f(p.z), sc.z, sh.z), 0.f);
    v.w = fmaxf(fmaf(bf2f(p.w), sc.w, sh.w), 0.f);
    ((float4*)out)[t] = v;
}

extern "C" void kernel_launch(void* const* d_in, const int* in_sizes, int n_in,
                              void* d_out, int out_size, void* d_ws, size_t ws_size,
                              hipStream_t stream) {
    const float* x      = (const float*)d_in[0];
    const int*   eidx   = (const int*)d_in[1];
    const float* W      = (const float*)d_in[2];
    const float* bias   = (const float*)d_in[3];
    const float* skipW  = (const float*)d_in[4];
    const float* gamma  = (const float*)d_in[5];
    const float* beta   = (const float*)d_in[6];
    float* out = (float*)d_out;
    float* ws  = (float*)d_ws;

    const int* row = eidx;
    const int* col = eidx + E_EDGES;

    float* scaleshift = ws + OFF_SCALE;
    float* dinv       = ws + OFF_DINV;
    int*   rowptr     = (int*)(ws + OFF_ROWPTR);
    int*   base       = (int*)(ws + OFF_BASE);
    int*   done       = (int*)(ws + OFF_DONE);
    int*   gh         = (int*)(ws + OFF_GHIST);
    float* partial    = ws + OFF_PART;            // aliases gh (dead after scatter)
    unsigned int* binned = (unsigned int*)(ws + OFF_BINNED);
    ushort* xb        = (ushort*)(ws + OFF_XB);
    ushort* u         = (ushort*)(ws + OFF_U);
    unsigned* xd8     = (unsigned*)(ws + OFF_XD8);  // aliases pre (dead by k_gemm)
    ushort* pre       = (ushort*)(ws + OFF_PRE);
    ushort* Bt        = (ushort*)(ws + OFF_BT);

    hipMemsetAsync(done, 0, 8, stream);

    k_hist<<<NCHUNK + 64, 256, 0, stream>>>(col, gh, W, skipW, Bt);
    k_scan_buckets<<<NBUCK, 512, 0, stream>>>(gh, base, rowptr, done);
    k_scatter_bin<<<NCHUNK, 256, 0, stream>>>(row, col, gh, base, binned);
    k_sortbucket<<<NBUCK, 256, 0, stream>>>(binned, base, rowptr, dinv, x, xb, xd8);
    k_agg<<<(N_PAD * 16 + 255) / 256, 256, 0, stream>>>(xd8, dinv, rowptr, binned, u);
    k_gemm<<<NBUCK, 256, 0, stream>>>(u, xb, Bt, bias, pre, partial);
    k_reduce<<<128, 256, 0, stream>>>(partial, gamma, beta, scaleshift);
    k_apply<<<(N_NODES * 32 + 255) / 256, 256, 0, stream>>>(pre, out, scaleshift);
}

// Round 10
// 217.442 us; speedup vs baseline: 1.2116x; 1.2116x over previous
//
#include <hip/hip_runtime.h>

// GCN layer: out = ReLU(BN(GCNConv(x) + x@skip_W))
// R10: revert R9's agent-scope scan fusion (each release/acquire forced an
//      L2 writeback on non-coherent XCD L2s -> 60us kernel). Scan is two
//      plain kernels again. Keep int4 edge reads, prep-in-hist, shfl sort
//      scan, fp8 gather, hoisted bf16 MFMA GEMM.

typedef unsigned short ushort;
typedef __bf16 bf16x8 __attribute__((ext_vector_type(8)));
typedef float f32x4 __attribute__((ext_vector_type(4)));
typedef float f32x2 __attribute__((ext_vector_type(2)));

constexpr int N_NODES = 100000;
constexpr int N_PAD   = 100096;                  // 782*128
constexpr int E_EDGES = 1600000;

constexpr int BUCK_SHIFT = 7;                    // 128 nodes per bucket
constexpr int NBUCK   = (N_NODES + 127) / 128;   // 782
constexpr int NBUCK_P = 784;
constexpr int CHUNK   = 4096;
constexpr int NCHUNK  = (E_EDGES + CHUNK - 1) / CHUNK;  // 391
constexpr int SORT_CAP = 4096;

// ws layout (4-byte element offsets)
constexpr size_t OFF_SCALE  = 0;         // 256 floats (scale/shift)
constexpr size_t OFF_DINV   = 256;       // N_PAD floats
constexpr size_t OFF_ROWPTR = 100352;    // N+1 ints
constexpr size_t OFF_BASE   = 200480;    // NBUCK+1 ints (pad 800)
constexpr size_t OFF_GHIST  = 201280;    // NCHUNK*NBUCK_P = 306544 ints
constexpr size_t OFF_PART   = OFF_GHIST; // 782*256 floats, aliases gh (dead post-scatter)
constexpr size_t OFF_BINNED = 507824;    // E ints (packed edges; csr in place)
constexpr size_t OFF_XB     = 2107824;   // N_PAD*64 ushort
constexpr size_t OFF_U      = 5310896;   // N_PAD*64 ushort
constexpr size_t OFF_PRE    = 8513968;   // N_PAD*128 ushort (bf16 pre-BN)
constexpr size_t OFF_XD8    = OFF_PRE;   // N_PAD*16 uints, aliases pre (dead by k_gemm)
constexpr size_t OFF_BT     = 14920112;  // 128*128 ushort

static __device__ __forceinline__ ushort f2bf(float f) {
    union { float f; unsigned u; } v; v.f = f;
    unsigned r = v.u + 0x7FFFu + ((v.u >> 16) & 1u);  // RNE
    return (ushort)(r >> 16);
}
static __device__ __forceinline__ float bf2f(ushort u) {
    union { unsigned u; float f; } v; v.u = (unsigned)u << 16;
    return v.f;
}
static __device__ __forceinline__ unsigned pack_fp8x4(float a, float b, float c, float d) {
    int r = 0;
    r = __builtin_amdgcn_cvt_pk_fp8_f32(a, b, r, false);
    r = __builtin_amdgcn_cvt_pk_fp8_f32(c, d, r, true);
    return (unsigned)r;
}

// ---- hist (blocks 0..NCHUNK-1) + Bt prep (blocks NCHUNK..NCHUNK+63) ----
__global__ __launch_bounds__(256) void k_hist(const int* __restrict__ col,
                                              int* __restrict__ gh,
                                              const float* __restrict__ W,
                                              const float* __restrict__ skipW,
                                              ushort* __restrict__ Bt) {
    int c = blockIdx.x, t = threadIdx.x;
    if (c >= NCHUNK) {  // prep: Bt[n][k] = bf16(B[k][n])
        int idx = (c - NCHUNK) * 256 + t;
        int k = idx >> 7, n = idx & 127;
        float v = (k < 64) ? W[k * 128 + n] : skipW[(k - 64) * 128 + n];
        Bt[n * 128 + k] = f2bf(v);
        return;
    }
    __shared__ int h[NBUCK_P];
    for (int b = t; b < NBUCK_P; b += 256) h[b] = 0;
    __syncthreads();
    const int4* col4 = (const int4*)col;
    int g0 = c * (CHUNK / 4);
#pragma unroll
    for (int i = 0; i < CHUNK / 1024; ++i) {
        int g4 = g0 + i * 256 + t;
        if (g4 * 4 + 3 < E_EDGES) {
            int4 cc = col4[g4];
            atomicAdd(&h[cc.x >> BUCK_SHIFT], 1);
            atomicAdd(&h[cc.y >> BUCK_SHIFT], 1);
            atomicAdd(&h[cc.z >> BUCK_SHIFT], 1);
            atomicAdd(&h[cc.w >> BUCK_SHIFT], 1);
        } else {
#pragma unroll
            for (int j = 0; j < 4; ++j) {
                int e = g4 * 4 + j;
                if (e < E_EDGES) atomicAdd(&h[col[e] >> BUCK_SHIFT], 1);
            }
        }
    }
    __syncthreads();
    for (int b = t; b < NBUCK_P; b += 256) gh[c * NBUCK_P + b] = h[b];
}

// ---- pass 2a: per-bucket exclusive scan over chunks; bucket totals ----
__global__ __launch_bounds__(512) void k_scan_buckets(int* __restrict__ gh,
                                                      int* __restrict__ base) {
    __shared__ int lds[512];
    int b = blockIdx.x, t = threadIdx.x;
    int v = (t < NCHUNK) ? gh[t * NBUCK_P + b] : 0;
    lds[t] = v;
    __syncthreads();
    int val = v;
#pragma unroll
    for (int off = 1; off < 512; off <<= 1) {
        int add = (t >= off) ? lds[t - off] : 0;
        __syncthreads();
        val += add;
        lds[t] = val;
        __syncthreads();
    }
    if (t < NCHUNK) gh[t * NBUCK_P + b] = val - v;  // exclusive within bucket
    if (t == 511) base[b] = val;                    // bucket total
}

// ---- pass 2b: exclusive scan of bucket totals -> bucket bases ----
__global__ __launch_bounds__(1024) void k_scan_bases(int* __restrict__ base,
                                                     int* __restrict__ rowptr) {
    __shared__ int lds[1024];
    int t = threadIdx.x;
    int v = (t < NBUCK) ? base[t] : 0;
    lds[t] = v;
    __syncthreads();
    int val = v;
#pragma unroll
    for (int off = 1; off < 1024; off <<= 1) {
        int add = (t >= off) ? lds[t - off] : 0;
        __syncthreads();
        val += add;
        lds[t] = val;
        __syncthreads();
    }
    if (t < NBUCK) base[t] = val - v;
    if (t == 1023) {
        base[NBUCK] = val;
        rowptr[N_NODES] = val;
    }
}

// ---- scatter edges into bucket-contiguous array (packed), int4 reads ----
__global__ __launch_bounds__(256) void k_scatter_bin(const int* __restrict__ row,
                                                     const int* __restrict__ col,
                                                     const int* __restrict__ gh,
                                                     const int* __restrict__ base,
                                                     unsigned int* __restrict__ binned) {
    __shared__ int cur[NBUCK_P];
    int c = blockIdx.x, t = threadIdx.x;
    for (int b = t; b < NBUCK_P; b += 256) {
        int bb = (b < NBUCK) ? base[b] : 0;
        cur[b] = bb + gh[c * NBUCK_P + b];
    }
    __syncthreads();
    const int4* col4 = (const int4*)col;
    const int4* row4 = (const int4*)row;
    int g0 = c * (CHUNK / 4);
#pragma unroll
    for (int i = 0; i < CHUNK / 1024; ++i) {
        int g4 = g0 + i * 256 + t;
        if (g4 * 4 + 3 < E_EDGES) {
            int4 cc = col4[g4];
            int4 rr = row4[g4];
            int p;
            p = atomicAdd(&cur[cc.x >> BUCK_SHIFT], 1);
            binned[p] = ((unsigned)(cc.x & 127) << 17) | (unsigned)rr.x;
            p = atomicAdd(&cur[cc.y >> BUCK_SHIFT], 1);
            binned[p] = ((unsigned)(cc.y & 127) << 17) | (unsigned)rr.y;
            p = atomicAdd(&cur[cc.z >> BUCK_SHIFT], 1);
            binned[p] = ((unsigned)(cc.z & 127) << 17) | (unsigned)rr.z;
            p = atomicAdd(&cur[cc.w >> BUCK_SHIFT], 1);
            binned[p] = ((unsigned)(cc.w & 127) << 17) | (unsigned)rr.w;
        } else {
#pragma unroll
            for (int j = 0; j < 4; ++j) {
                int e = g4 * 4 + j;
                if (e < E_EDGES) {
                    int d = col[e], s = row[e];
                    int p = atomicAdd(&cur[d >> BUCK_SHIFT], 1);
                    binned[p] = ((unsigned)(d & 127) << 17) | (unsigned)s;
                }
            }
        }
    }
}

// ---- per-bucket counting sort (shfl scan) -> csr, rowptr, dinv; fused cast ----
__global__ __launch_bounds__(256) void k_sortbucket(unsigned int* __restrict__ binned,
                                                    const int* __restrict__ base,
                                                    int* __restrict__ rowptr,
                                                    float* __restrict__ dinv,
                                                    const float* __restrict__ x,
                                                    ushort* __restrict__ xb,
                                                    unsigned* __restrict__ xd8) {
    __shared__ unsigned int ebuf[SORT_CAP];
    __shared__ int sbuf[SORT_CAP];
    __shared__ int lcnt[128];
    __shared__ int lptr[128];
    __shared__ float ldinv[128];
    __shared__ int wsum[2];
    int b = blockIdx.x, t = threadIdx.x;
    int i0 = base[b], i1 = base[b + 1];
    int cnt = i1 - i0;
    if (cnt > SORT_CAP) cnt = SORT_CAP;
    int n0 = b << BUCK_SHIFT;
    int nn = min(128, N_NODES - n0);

    for (int k = t; k < cnt; k += 256) ebuf[k] = binned[i0 + k];
    if (t < 128) lcnt[t] = 0;
    __syncthreads();
    for (int k = t; k < cnt; k += 256) atomicAdd(&lcnt[ebuf[k] >> 17], 1);
    __syncthreads();

    // 128-wide exclusive scan via 2-wave shfl
    int myc = 0, val = 0;
    if (t < 128) {
        myc = lcnt[t];
        val = myc;
#pragma unroll
        for (int d = 1; d < 64; d <<= 1) {
            int o = __shfl_up(val, d);
            if ((t & 63) >= d) val += o;
        }
        if ((t & 63) == 63) wsum[t >> 6] = val;
    }
    __syncthreads();
    if (t < 128) {
        if (t >= 64) val += wsum[0];
        int excl = val - myc;
        lptr[t] = excl;
        float dv = rsqrtf((float)myc + 1.0f);  // +1 self loop
        ldinv[t] = dv;
        if (t < nn) {
            rowptr[n0 + t] = i0 + excl;
            dinv[n0 + t] = dv;
        }
    }
    __syncthreads();
    for (int k = t; k < cnt; k += 256) {
        unsigned int e = ebuf[k];
        int j = (int)(e >> 17);
        int p = atomicAdd(&lptr[j], 1);
        sbuf[p] = (int)(e & 0x1FFFF);
    }
    __syncthreads();
    for (int k = t; k < cnt; k += 256) binned[i0 + k] = (unsigned int)sbuf[k];

    // fused cast: this bucket's 128 node rows -> xb (bf16), xd8 (fp8*dinv)
#pragma unroll
    for (int it = 0; it < 8; ++it) {
        int idx = it * 256 + t;          // 0..2047
        int nl = idx >> 4, q = idx & 15;
        int c = n0 + nl;
        ushort4 bb = {0, 0, 0, 0};
        unsigned w8 = 0;
        if (nl < nn) {
            float4 v = ((const float4*)x)[(size_t)c * 16 + q];
            bb.x = f2bf(v.x); bb.y = f2bf(v.y); bb.z = f2bf(v.z); bb.w = f2bf(v.w);
            float d = ldinv[nl];
            w8 = pack_fp8x4(v.x * d, v.y * d, v.z * d, v.w * d);
        }
        ((ushort4*)xb)[(size_t)c * 16 + q] = bb;
        xd8[(size_t)c * 16 + q] = w8;
    }
}

// ---- aggregation: 16 lanes per node; fp8 gather (1 line/edge), unroll-8 ----
__global__ __launch_bounds__(256) void k_agg(const unsigned* __restrict__ xd8,
                                             const float* __restrict__ dinv,
                                             const int* __restrict__ rowptr,
                                             const unsigned int* __restrict__ csr,
                                             ushort* __restrict__ u) {
    int t = blockIdx.x * blockDim.x + threadIdx.x;
    if (t >= N_PAD * 16) return;
    int c = t >> 4;
    int q = t & 15;
    if (c >= N_NODES) {
        ushort4 z = {0, 0, 0, 0};
        ((ushort4*)u)[t] = z;
        return;
    }
    float dc = dinv[c];
    float4 acc;
    {
        unsigned w = xd8[t];
        f32x2 lo = __builtin_amdgcn_cvt_pk_f32_fp8((int)w, false);
        f32x2 hi = __builtin_amdgcn_cvt_pk_f32_fp8((int)w, true);
        acc.x = lo.x; acc.y = lo.y; acc.z = hi.x; acc.w = hi.y;
    }
    int i0 = rowptr[c], i1 = rowptr[c + 1];
    int i = i0;
    for (; i + 8 <= i1; i += 8) {
        int s[8];
#pragma unroll
        for (int k = 0; k < 8; ++k) s[k] = (int)csr[i + k];
        unsigned w[8];
#pragma unroll
        for (int k = 0; k < 8; ++k) w[k] = xd8[s[k] * 16 + q];
#pragma unroll
        for (int k = 0; k < 8; ++k) {
            f32x2 lo = __builtin_amdgcn_cvt_pk_f32_fp8((int)w[k], false);
            f32x2 hi = __builtin_amdgcn_cvt_pk_f32_fp8((int)w[k], true);
            acc.x += lo.x; acc.y += lo.y; acc.z += hi.x; acc.w += hi.y;
        }
    }
    for (; i < i1; ++i) {
        unsigned w = xd8[(int)csr[i] * 16 + q];
        f32x2 lo = __builtin_amdgcn_cvt_pk_f32_fp8((int)w, false);
        f32x2 hi = __builtin_amdgcn_cvt_pk_f32_fp8((int)w, true);
        acc.x += lo.x; acc.y += lo.y; acc.z += hi.x; acc.w += hi.y;
    }
    ushort4 o;
    o.x = f2bf(acc.x * dc); o.y = f2bf(acc.y * dc);
    o.z = f2bf(acc.z * dc); o.w = f2bf(acc.w * dc);
    ((ushort4*)u)[t] = o;
}

// ---- MFMA GEMM: pre = [u|xb] @ Bt^T + bias (bf16 out); per-block partials ----
__global__ __launch_bounds__(256) void k_gemm(const ushort* __restrict__ u,
                                              const ushort* __restrict__ xb,
                                              const ushort* __restrict__ Bt,
                                              const float* __restrict__ bias,
                                              ushort* __restrict__ pre,
                                              float* __restrict__ partial) {
    __shared__ float sred[128];
    __shared__ float qred[128];
    int tid = threadIdx.x;
    int wave = tid >> 6, lane = tid & 63;
    int wm = wave >> 1, wn = wave & 1;
    int l15 = lane & 15, quad = lane >> 4;
    int row0 = blockIdx.x * 128 + wm * 64;
    int col0 = wn * 64;

    if (tid < 128) { sred[tid] = 0.f; qred[tid] = 0.f; }
    __syncthreads();

    bf16x8 af[4][4], bf_[4][4];
#pragma unroll
    for (int kc = 0; kc < 4; ++kc) {
        const ushort* abase = (kc < 2) ? u : xb;
        int ko = (kc & 1) * 32 + quad * 8;
#pragma unroll
        for (int im = 0; im < 4; ++im)
            af[kc][im] = *(const bf16x8*)&abase[(size_t)(row0 + im * 16 + l15) * 64 + ko];
#pragma unroll
        for (int jn = 0; jn < 4; ++jn)
            bf_[kc][jn] = *(const bf16x8*)&Bt[(size_t)(col0 + jn * 16 + l15) * 128 + kc * 32 + quad * 8];
    }

    f32x4 acc[4][4];
#pragma unroll
    for (int a = 0; a < 4; ++a)
#pragma unroll
        for (int b = 0; b < 4; ++b) acc[a][b] = (f32x4){0.f, 0.f, 0.f, 0.f};

#pragma unroll
    for (int kc = 0; kc < 4; ++kc)
#pragma unroll
        for (int im = 0; im < 4; ++im)
#pragma unroll
            for (int jn = 0; jn < 4; ++jn)
                acc[im][jn] = __builtin_amdgcn_mfma_f32_16x16x32_bf16(
                    af[kc][im], bf_[kc][jn], acc[im][jn], 0, 0, 0);

    int coln[4];
    float bi[4];
#pragma unroll
    for (int jn = 0; jn < 4; ++jn) {
        coln[jn] = col0 + jn * 16 + l15;
        bi[jn] = bias[coln[jn]];
    }
    float lsum[4] = {0.f, 0.f, 0.f, 0.f};
    float lsq[4]  = {0.f, 0.f, 0.f, 0.f};
#pragma unroll
    for (int im = 0; im < 4; ++im) {
        int rbase = row0 + im * 16 + quad * 4;
#pragma unroll
        for (int r = 0; r < 4; ++r) {
            int rowi = rbase + r;
            if (rowi < N_NODES) {
#pragma unroll
                for (int jn = 0; jn < 4; ++jn) {
                    float v = acc[im][jn][r] + bi[jn];
                    pre[(size_t)rowi * 128 + coln[jn]] = f2bf(v);
                    lsum[jn] += v;
                    lsq[jn]  += v * v;
                }
            }
        }
    }
#pragma unroll
    for (int jn = 0; jn < 4; ++jn) {
        atomicAdd(&sred[coln[jn]], lsum[jn]);
        atomicAdd(&qred[coln[jn]], lsq[jn]);
    }
    __syncthreads();
    if (tid < 128) {
        partial[(size_t)blockIdx.x * 256 + tid]       = sred[tid];
        partial[(size_t)blockIdx.x * 256 + 128 + tid] = qred[tid];
    }
}

// ---- reduce 782 partials -> scale/shift (one block per output column) ----
__global__ __launch_bounds__(256) void k_reduce(const float* __restrict__ partial,
                                                const float* __restrict__ gamma,
                                                const float* __restrict__ beta,
                                                float* __restrict__ scaleshift) {
    __shared__ float ls[256], lq[256];
    int j = blockIdx.x;   // 0..127
    int t = threadIdx.x;
    float s = 0.f, q = 0.f;
    for (int p = t; p < NBUCK; p += 256) {
        s += partial[(size_t)p * 256 + j];
        q += partial[(size_t)p * 256 + 128 + j];
    }
    ls[t] = s; lq[t] = q;
    __syncthreads();
#pragma unroll
    for (int off = 128; off > 0; off >>= 1) {
        if (t < off) { ls[t] += ls[t + off]; lq[t] += lq[t + off]; }
        __syncthreads();
    }
    if (t == 0) {
        float mean = ls[0] * (1.0f / N_NODES);
        float var  = lq[0] * (1.0f / N_NODES) - mean * mean;
        float sc   = gamma[j] * rsqrtf(var + 1e-5f);
        scaleshift[j]       = sc;
        scaleshift[128 + j] = beta[j] - mean * sc;
    }
}

// read bf16 pre, write fp32 out
__global__ void k_apply(const ushort* __restrict__ pre, float* __restrict__ out,
                        const float* __restrict__ scaleshift) {
    int t = blockIdx.x * blockDim.x + threadIdx.x;
    if (t >= N_NODES * 32) return;
    int j4 = t & 31;
    ushort4 p = ((const ushort4*)pre)[t];
    float4 sc = ((const float4*)scaleshift)[j4];
    float4 sh = ((const float4*)(scaleshift + 128))[j4];
    float4 v;
    v.x = fmaxf(fmaf(bf2f(p.x), sc.x, sh.x), 0.f);
    v.y = fmaxf(fmaf(bf2f(p.y), sc.y, sh.y), 0.f);
    v.z = fmaxf(fmaf(bf2f(p.z), sc.z, sh.z), 0.f);
    v.w = fmaxf(fmaf(bf2f(p.w), sc.w, sh.w), 0.f);
    ((float4*)out)[t] = v;
}

extern "C" void kernel_launch(void* const* d_in, const int* in_sizes, int n_in,
                              void* d_out, int out_size, void* d_ws, size_t ws_size,
                              hipStream_t stream) {
    const float* x      = (const float*)d_in[0];
    const int*   eidx   = (const int*)d_in[1];
    const float* W      = (const float*)d_in[2];
    const float* bias   = (const float*)d_in[3];
    const float* skipW  = (const float*)d_in[4];
    const float* gamma  = (const float*)d_in[5];
    const float* beta   = (const float*)d_in[6];
    float* out = (float*)d_out;
    float* ws  = (float*)d_ws;

    const int* row = eidx;
    const int* col = eidx + E_EDGES;

    float* scaleshift = ws + OFF_SCALE;
    float* dinv       = ws + OFF_DINV;
    int*   rowptr     = (int*)(ws + OFF_ROWPTR);
    int*   base       = (int*)(ws + OFF_BASE);
    int*   gh         = (int*)(ws + OFF_GHIST);
    float* partial    = ws + OFF_PART;            // aliases gh (dead after scatter)
    unsigned int* binned = (unsigned int*)(ws + OFF_BINNED);
    ushort* xb        = (ushort*)(ws + OFF_XB);
    ushort* u         = (ushort*)(ws + OFF_U);
    unsigned* xd8     = (unsigned*)(ws + OFF_XD8);  // aliases pre (dead by k_gemm)
    ushort* pre       = (ushort*)(ws + OFF_PRE);
    ushort* Bt        = (ushort*)(ws + OFF_BT);

    k_hist<<<NCHUNK + 64, 256, 0, stream>>>(col, gh, W, skipW, Bt);
    k_scan_buckets<<<NBUCK, 512, 0, stream>>>(gh, base);
    k_scan_bases<<<1, 1024, 0, stream>>>(base, rowptr);
    k_scatter_bin<<<NCHUNK, 256, 0, stream>>>(row, col, gh, base, binned);
    k_sortbucket<<<NBUCK, 256, 0, stream>>>(binned, base, rowptr, dinv, x, xb, xd8);
    k_agg<<<(N_PAD * 16 + 255) / 256, 256, 0, stream>>>(xd8, dinv, rowptr, binned, u);
    k_gemm<<<NBUCK, 256, 0, stream>>>(u, xb, Bt, bias, pre, partial);
    k_reduce<<<128, 256, 0, stream>>>(partial, gamma, beta, scaleshift);
    k_apply<<<(N_NODES * 32 + 255) / 256, 256, 0, stream>>>(pre, out, scaleshift);
}

// Round 12
// 210.038 us; speedup vs baseline: 1.2543x; 1.0353x over previous
//
#include <hip/hip_runtime.h>

// GCN layer: out = ReLU(BN(GCNConv(x) + x@skip_W))
// R12: R11 logic with FIXED ws layout (R11 under-allocated u by 2x ->
//      agg's u writes stomped xd8 mid-gather). Transposed chunk-histogram
//      (wave-shfl scan), CHUNK=8192, gemm converts fp32 x in-register,
//      fp8 gather, hoisted bf16 MFMA GEMM, per-block BN partials.

typedef unsigned short ushort;
typedef __bf16 bf16x8 __attribute__((ext_vector_type(8)));
typedef float f32x4 __attribute__((ext_vector_type(4)));
typedef float f32x2 __attribute__((ext_vector_type(2)));

constexpr int N_NODES = 100000;
constexpr int N_PAD   = 100096;                  // 782*128
constexpr int E_EDGES = 1600000;

constexpr int BUCK_SHIFT = 7;                    // 128 nodes per bucket
constexpr int NBUCK   = (N_NODES + 127) / 128;   // 782
constexpr int NBUCK_P = 784;
constexpr int CHUNK   = 8192;
constexpr int NCHUNK  = (E_EDGES + CHUNK - 1) / CHUNK;  // 196
constexpr int GH_STRIDE = 200;                   // padded chunk-count per bucket
constexpr int SORT_CAP = 4096;

// ws layout (4-byte element offsets) — sizes audited:
//   scale 256 | dinv 100096 | rowptr 100128 | base 800 | gh 156800 |
//   binned 1600000 (aliased by partial 200192 after agg) |
//   u 3203072 (N_PAD*64 ushort) | pre 6406144 (N_PAD*128 ushort,
//   aliased by xd8 1601536 uints before gemm) | Bt 8192
constexpr size_t OFF_SCALE  = 0;
constexpr size_t OFF_DINV   = 256;
constexpr size_t OFF_ROWPTR = 100352;
constexpr size_t OFF_BASE   = 200480;
constexpr size_t OFF_GHIST  = 201280;    // ends 358080
constexpr size_t OFF_BINNED = 358080;    // ends 1958080
constexpr size_t OFF_PART   = OFF_BINNED;
constexpr size_t OFF_U      = 1958080;   // ends 5161152
constexpr size_t OFF_PRE    = 5161152;   // ends 11567296
constexpr size_t OFF_XD8    = OFF_PRE;
constexpr size_t OFF_BT     = 11567296;  // ends 11575488

static __device__ __forceinline__ ushort f2bf(float f) {
    union { float f; unsigned u; } v; v.f = f;
    unsigned r = v.u + 0x7FFFu + ((v.u >> 16) & 1u);  // RNE
    return (ushort)(r >> 16);
}
static __device__ __forceinline__ float bf2f(ushort u) {
    union { unsigned u; float f; } v; v.u = (unsigned)u << 16;
    return v.f;
}
static __device__ __forceinline__ unsigned pack_fp8x4(float a, float b, float c, float d) {
    int r = 0;
    r = __builtin_amdgcn_cvt_pk_fp8_f32(a, b, r, false);
    r = __builtin_amdgcn_cvt_pk_fp8_f32(c, d, r, true);
    return (unsigned)r;
}
static __device__ __forceinline__ bf16x8 pack_bf8(float4 a, float4 b) {
    union { ushort us[8]; bf16x8 v; } u;
    u.us[0] = f2bf(a.x); u.us[1] = f2bf(a.y); u.us[2] = f2bf(a.z); u.us[3] = f2bf(a.w);
    u.us[4] = f2bf(b.x); u.us[5] = f2bf(b.y); u.us[6] = f2bf(b.z); u.us[7] = f2bf(b.w);
    return u.v;
}

// ---- hist (blocks 0..NCHUNK-1, transposed write) + Bt prep (last 64 blocks) ----
__global__ __launch_bounds__(256) void k_hist(const int* __restrict__ col,
                                              int* __restrict__ gh_t,
                                              const float* __restrict__ W,
                                              const float* __restrict__ skipW,
                                              ushort* __restrict__ Bt) {
    int c = blockIdx.x, t = threadIdx.x;
    if (c >= NCHUNK) {  // prep: Bt[n][k] = bf16(B[k][n])
        int idx = (c - NCHUNK) * 256 + t;
        int k = idx >> 7, n = idx & 127;
        float v = (k < 64) ? W[k * 128 + n] : skipW[(k - 64) * 128 + n];
        Bt[n * 128 + k] = f2bf(v);
        return;
    }
    __shared__ int h[NBUCK_P];
    for (int b = t; b < NBUCK_P; b += 256) h[b] = 0;
    __syncthreads();
    const int4* col4 = (const int4*)col;
    int g0 = c * (CHUNK / 4);
#pragma unroll
    for (int i = 0; i < CHUNK / 1024; ++i) {
        int g4 = g0 + i * 256 + t;
        if (g4 * 4 + 3 < E_EDGES) {
            int4 cc = col4[g4];
            atomicAdd(&h[cc.x >> BUCK_SHIFT], 1);
            atomicAdd(&h[cc.y >> BUCK_SHIFT], 1);
            atomicAdd(&h[cc.z >> BUCK_SHIFT], 1);
            atomicAdd(&h[cc.w >> BUCK_SHIFT], 1);
        } else {
#pragma unroll
            for (int j = 0; j < 4; ++j) {
                int e = g4 * 4 + j;
                if (e < E_EDGES) atomicAdd(&h[col[e] >> BUCK_SHIFT], 1);
            }
        }
    }
    __syncthreads();
    for (int b = t; b < NBUCK_P; b += 256) gh_t[(size_t)b * GH_STRIDE + c] = h[b];
}

// ---- wave-per-bucket exclusive scan over chunks (contiguous, barrier-free) ----
__global__ __launch_bounds__(256) void k_scan_chunks(int* __restrict__ gh_t,
                                                     int* __restrict__ base) {
    int w = threadIdx.x >> 6, l = threadIdx.x & 63;
    int b = blockIdx.x * 4 + w;          // 196 blocks x 4 waves = 784
    if (b >= NBUCK_P) return;
    int* rowp = gh_t + (size_t)b * GH_STRIDE;
    int carry = 0;
#pragma unroll
    for (int i = 0; i < 4; ++i) {        // 4*64 = 256 >= NCHUNK
        int idx = i * 64 + l;
        int v = (idx < NCHUNK) ? rowp[idx] : 0;
        int orig = v;
#pragma unroll
        for (int d = 1; d < 64; d <<= 1) {
            int o = __shfl_up(v, d);
            if (l >= d) v += o;
        }
        if (idx < NCHUNK) rowp[idx] = carry + v - orig;  // exclusive
        carry += __shfl(v, 63);
    }
    if (l == 0 && b < NBUCK) base[b] = carry;            // bucket total
}

// ---- exclusive scan of bucket totals -> bucket bases ----
__global__ __launch_bounds__(1024) void k_scan_bases(int* __restrict__ base,
                                                     int* __restrict__ rowptr) {
    __shared__ int lds[1024];
    int t = threadIdx.x;
    int v = (t < NBUCK) ? base[t] : 0;
    lds[t] = v;
    __syncthreads();
    int val = v;
#pragma unroll
    for (int off = 1; off < 1024; off <<= 1) {
        int add = (t >= off) ? lds[t - off] : 0;
        __syncthreads();
        val += add;
        lds[t] = val;
        __syncthreads();
    }
    if (t < NBUCK) base[t] = val - v;
    if (t == 1023) {
        base[NBUCK] = val;
        rowptr[N_NODES] = val;
    }
}

// ---- scatter edges into bucket-contiguous array (packed), int4 reads ----
__global__ __launch_bounds__(256) void k_scatter_bin(const int* __restrict__ row,
                                                     const int* __restrict__ col,
                                                     const int* __restrict__ gh_t,
                                                     const int* __restrict__ base,
                                                     unsigned int* __restrict__ binned) {
    __shared__ int cur[NBUCK_P];
    int c = blockIdx.x, t = threadIdx.x;
    for (int b = t; b < NBUCK_P; b += 256) {
        int bb = (b < NBUCK) ? base[b] : 0;
        cur[b] = bb + gh_t[(size_t)b * GH_STRIDE + c];
    }
    __syncthreads();
    const int4* col4 = (const int4*)col;
    const int4* row4 = (const int4*)row;
    int g0 = c * (CHUNK / 4);
#pragma unroll
    for (int i = 0; i < CHUNK / 1024; ++i) {
        int g4 = g0 + i * 256 + t;
        if (g4 * 4 + 3 < E_EDGES) {
            int4 cc = col4[g4];
            int4 rr = row4[g4];
            int p;
            p = atomicAdd(&cur[cc.x >> BUCK_SHIFT], 1);
            binned[p] = ((unsigned)(cc.x & 127) << 17) | (unsigned)rr.x;
            p = atomicAdd(&cur[cc.y >> BUCK_SHIFT], 1);
            binned[p] = ((unsigned)(cc.y & 127) << 17) | (unsigned)rr.y;
            p = atomicAdd(&cur[cc.z >> BUCK_SHIFT], 1);
            binned[p] = ((unsigned)(cc.z & 127) << 17) | (unsigned)rr.z;
            p = atomicAdd(&cur[cc.w >> BUCK_SHIFT], 1);
            binned[p] = ((unsigned)(cc.w & 127) << 17) | (unsigned)rr.w;
        } else {
#pragma unroll
            for (int j = 0; j < 4; ++j) {
                int e = g4 * 4 + j;
                if (e < E_EDGES) {
                    int d = col[e], s = row[e];
                    int p = atomicAdd(&cur[d >> BUCK_SHIFT], 1);
                    binned[p] = ((unsigned)(d & 127) << 17) | (unsigned)s;
                }
            }
        }
    }
}

// ---- per-bucket counting sort (shfl scan) -> csr, rowptr, dinv; fused fp8 cast ----
__global__ __launch_bounds__(256) void k_sortbucket(unsigned int* __restrict__ binned,
                                                    const int* __restrict__ base,
                                                    int* __restrict__ rowptr,
                                                    float* __restrict__ dinv,
                                                    const float* __restrict__ x,
                                                    unsigned* __restrict__ xd8) {
    __shared__ unsigned int ebuf[SORT_CAP];
    __shared__ int sbuf[SORT_CAP];
    __shared__ int lcnt[128];
    __shared__ int lptr[128];
    __shared__ float ldinv[128];
    __shared__ int wsum[2];
    int b = blockIdx.x, t = threadIdx.x;
    int i0 = base[b], i1 = base[b + 1];
    int cnt = i1 - i0;
    if (cnt > SORT_CAP) cnt = SORT_CAP;
    int n0 = b << BUCK_SHIFT;
    int nn = min(128, N_NODES - n0);

    for (int k = t; k < cnt; k += 256) ebuf[k] = binned[i0 + k];
    if (t < 128) lcnt[t] = 0;
    __syncthreads();
    for (int k = t; k < cnt; k += 256) atomicAdd(&lcnt[ebuf[k] >> 17], 1);
    __syncthreads();

    // 128-wide exclusive scan via 2-wave shfl
    int myc = 0, val = 0;
    if (t < 128) {
        myc = lcnt[t];
        val = myc;
#pragma unroll
        for (int d = 1; d < 64; d <<= 1) {
            int o = __shfl_up(val, d);
            if ((t & 63) >= d) val += o;
        }
        if ((t & 63) == 63) wsum[t >> 6] = val;
    }
    __syncthreads();
    if (t < 128) {
        if (t >= 64) val += wsum[0];
        int excl = val - myc;
        lptr[t] = excl;
        float dv = rsqrtf((float)myc + 1.0f);  // +1 self loop
        ldinv[t] = dv;
        if (t < nn) {
            rowptr[n0 + t] = i0 + excl;
            dinv[n0 + t] = dv;
        }
    }
    __syncthreads();
    for (int k = t; k < cnt; k += 256) {
        unsigned int e = ebuf[k];
        int j = (int)(e >> 17);
        int p = atomicAdd(&lptr[j], 1);
        sbuf[p] = (int)(e & 0x1FFFF);
    }
    __syncthreads();
    for (int k = t; k < cnt; k += 256) binned[i0 + k] = (unsigned int)sbuf[k];

    // fused cast: this bucket's 128 node rows -> xd8 (fp8 of x*dinv)
#pragma unroll
    for (int it = 0; it < 8; ++it) {
        int idx = it * 256 + t;          // 0..2047
        int nl = idx >> 4, q = idx & 15;
        int c = n0 + nl;
        unsigned w8 = 0;
        if (nl < nn) {
            float4 v = ((const float4*)x)[(size_t)c * 16 + q];
            float d = ldinv[nl];
            w8 = pack_fp8x4(v.x * d, v.y * d, v.z * d, v.w * d);
        }
        xd8[(size_t)c * 16 + q] = w8;
    }
}

// ---- aggregation: 16 lanes per node; fp8 gather (1 line/edge), unroll-8 ----
__global__ __launch_bounds__(256) void k_agg(const unsigned* __restrict__ xd8,
                                             const float* __restrict__ dinv,
                                             const int* __restrict__ rowptr,
                                             const unsigned int* __restrict__ csr,
                                             ushort* __restrict__ u) {
    int t = blockIdx.x * blockDim.x + threadIdx.x;
    if (t >= N_PAD * 16) return;
    int c = t >> 4;
    int q = t & 15;
    if (c >= N_NODES) {
        ushort4 z = {0, 0, 0, 0};
        ((ushort4*)u)[t] = z;
        return;
    }
    float dc = dinv[c];
    float4 acc;
    {
        unsigned w = xd8[t];
        f32x2 lo = __builtin_amdgcn_cvt_pk_f32_fp8((int)w, false);
        f32x2 hi = __builtin_amdgcn_cvt_pk_f32_fp8((int)w, true);
        acc.x = lo.x; acc.y = lo.y; acc.z = hi.x; acc.w = hi.y;
    }
    int i0 = rowptr[c], i1 = rowptr[c + 1];
    int i = i0;
    for (; i + 8 <= i1; i += 8) {
        int s[8];
#pragma unroll
        for (int k = 0; k < 8; ++k) s[k] = (int)csr[i + k];
        unsigned w[8];
#pragma unroll
        for (int k = 0; k < 8; ++k) w[k] = xd8[s[k] * 16 + q];
#pragma unroll
        for (int k = 0; k < 8; ++k) {
            f32x2 lo = __builtin_amdgcn_cvt_pk_f32_fp8((int)w[k], false);
            f32x2 hi = __builtin_amdgcn_cvt_pk_f32_fp8((int)w[k], true);
            acc.x += lo.x; acc.y += lo.y; acc.z += hi.x; acc.w += hi.y;
        }
    }
    for (; i < i1; ++i) {
        unsigned w = xd8[(int)csr[i] * 16 + q];
        f32x2 lo = __builtin_amdgcn_cvt_pk_f32_fp8((int)w, false);
        f32x2 hi = __builtin_amdgcn_cvt_pk_f32_fp8((int)w, true);
        acc.x += lo.x; acc.y += lo.y; acc.z += hi.x; acc.w += hi.y;
    }
    ushort4 o;
    o.x = f2bf(acc.x * dc); o.y = f2bf(acc.y * dc);
    o.z = f2bf(acc.z * dc); o.w = f2bf(acc.w * dc);
    ((ushort4*)u)[t] = o;
}

// ---- MFMA GEMM: pre = [u | bf16(x)] @ Bt^T + bias (bf16 out); BN partials ----
__global__ __launch_bounds__(256) void k_gemm(const ushort* __restrict__ u,
                                              const float* __restrict__ x,
                                              const ushort* __restrict__ Bt,
                                              const float* __restrict__ bias,
                                              ushort* __restrict__ pre,
                                              float* __restrict__ partial) {
    __shared__ float sred[128];
    __shared__ float qred[128];
    int tid = threadIdx.x;
    int wave = tid >> 6, lane = tid & 63;
    int wm = wave >> 1, wn = wave & 1;
    int l15 = lane & 15, quad = lane >> 4;
    int row0 = blockIdx.x * 128 + wm * 64;
    int col0 = wn * 64;

    if (tid < 128) { sred[tid] = 0.f; qred[tid] = 0.f; }
    __syncthreads();

    bf16x8 af[4][4], bf_[4][4];
#pragma unroll
    for (int kc = 0; kc < 2; ++kc) {
        int ko = kc * 32 + quad * 8;
#pragma unroll
        for (int im = 0; im < 4; ++im)
            af[kc][im] = *(const bf16x8*)&u[(size_t)(row0 + im * 16 + l15) * 64 + ko];
    }
#pragma unroll
    for (int kc = 2; kc < 4; ++kc) {
        int ko = (kc - 2) * 32 + quad * 8;
#pragma unroll
        for (int im = 0; im < 4; ++im) {
            int r = row0 + im * 16 + l15;
            float4 v0 = make_float4(0.f, 0.f, 0.f, 0.f);
            float4 v1 = v0;
            if (r < N_NODES) {
                v0 = *(const float4*)&x[(size_t)r * 64 + ko];
                v1 = *(const float4*)&x[(size_t)r * 64 + ko + 4];
            }
            af[kc][im] = pack_bf8(v0, v1);
        }
    }
#pragma unroll
    for (int kc = 0; kc < 4; ++kc)
#pragma unroll
        for (int jn = 0; jn < 4; ++jn)
            bf_[kc][jn] = *(const bf16x8*)&Bt[(size_t)(col0 + jn * 16 + l15) * 128 + kc * 32 + quad * 8];

    f32x4 acc[4][4];
#pragma unroll
    for (int a = 0; a < 4; ++a)
#pragma unroll
        for (int b = 0; b < 4; ++b) acc[a][b] = (f32x4){0.f, 0.f, 0.f, 0.f};

#pragma unroll
    for (int kc = 0; kc < 4; ++kc)
#pragma unroll
        for (int im = 0; im < 4; ++im)
#pragma unroll
            for (int jn = 0; jn < 4; ++jn)
                acc[im][jn] = __builtin_amdgcn_mfma_f32_16x16x32_bf16(
                    af[kc][im], bf_[kc][jn], acc[im][jn], 0, 0, 0);

    int coln[4];
    float bi[4];
#pragma unroll
    for (int jn = 0; jn < 4; ++jn) {
        coln[jn] = col0 + jn * 16 + l15;
        bi[jn] = bias[coln[jn]];
    }
    float lsum[4] = {0.f, 0.f, 0.f, 0.f};
    float lsq[4]  = {0.f, 0.f, 0.f, 0.f};
#pragma unroll
    for (int im = 0; im < 4; ++im) {
        int rbase = row0 + im * 16 + quad * 4;
#pragma unroll
        for (int r = 0; r < 4; ++r) {
            int rowi = rbase + r;
            if (rowi < N_NODES) {
#pragma unroll
                for (int jn = 0; jn < 4; ++jn) {
                    float v = acc[im][jn][r] + bi[jn];
                    pre[(size_t)rowi * 128 + coln[jn]] = f2bf(v);
                    lsum[jn] += v;
                    lsq[jn]  += v * v;
                }
            }
        }
    }
#pragma unroll
    for (int jn = 0; jn < 4; ++jn) {
        atomicAdd(&sred[coln[jn]], lsum[jn]);
        atomicAdd(&qred[coln[jn]], lsq[jn]);
    }
    __syncthreads();
    if (tid < 128) {
        partial[(size_t)blockIdx.x * 256 + tid]       = sred[tid];
        partial[(size_t)blockIdx.x * 256 + 128 + tid] = qred[tid];
    }
}

// ---- reduce 782 partials -> scale/shift (one block per output column) ----
__global__ __launch_bounds__(256) void k_reduce(const float* __restrict__ partial,
                                                const float* __restrict__ gamma,
                                                const float* __restrict__ beta,
                                                float* __restrict__ scaleshift) {
    __shared__ float ls[256], lq[256];
    int j = blockIdx.x;   // 0..127
    int t = threadIdx.x;
    float s = 0.f, q = 0.f;
    for (int p = t; p < NBUCK; p += 256) {
        s += partial[(size_t)p * 256 + j];
        q += partial[(size_t)p * 256 + 128 + j];
    }
    ls[t] = s; lq[t] = q;
    __syncthreads();
#pragma unroll
    for (int off = 128; off > 0; off >>= 1) {
        if (t < off) { ls[t] += ls[t + off]; lq[t] += lq[t + off]; }
        __syncthreads();
    }
    if (t == 0) {
        float mean = ls[0] * (1.0f / N_NODES);
        float var  = lq[0] * (1.0f / N_NODES) - mean * mean;
        float sc   = gamma[j] * rsqrtf(var + 1e-5f);
        scaleshift[j]       = sc;
        scaleshift[128 + j] = beta[j] - mean * sc;
    }
}

// read bf16 pre, write fp32 out
__global__ void k_apply(const ushort* __restrict__ pre, float* __restrict__ out,
                        const float* __restrict__ scaleshift) {
    int t = blockIdx.x * blockDim.x + threadIdx.x;
    if (t >= N_NODES * 32) return;
    int j4 = t & 31;
    ushort4 p = ((const ushort4*)pre)[t];
    float4 sc = ((const float4*)scaleshift)[j4];
    float4 sh = ((const float4*)(scaleshift + 128))[j4];
    float4 v;
    v.x = fmaxf(fmaf(bf2f(p.x), sc.x, sh.x), 0.f);
    v.y = fmaxf(fmaf(bf2f(p.y), sc.y, sh.y), 0.f);
    v.z = fmaxf(fmaf(bf2f(p.z), sc.z, sh.z), 0.f);
    v.w = fmaxf(fmaf(bf2f(p.w), sc.w, sh.w), 0.f);
    ((float4*)out)[t] = v;
}

extern "C" void kernel_launch(void* const* d_in, const int* in_sizes, int n_in,
                              void* d_out, int out_size, void* d_ws, size_t ws_size,
                              hipStream_t stream) {
    const float* x      = (const float*)d_in[0];
    const int*   eidx   = (const int*)d_in[1];
    const float* W      = (const float*)d_in[2];
    const float* bias   = (const float*)d_in[3];
    const float* skipW  = (const float*)d_in[4];
    const float* gamma  = (const float*)d_in[5];
    const float* beta   = (const float*)d_in[6];
    float* out = (float*)d_out;
    float* ws  = (float*)d_ws;

    const int* row = eidx;
    const int* col = eidx + E_EDGES;

    float* scaleshift = ws + OFF_SCALE;
    float* dinv       = ws + OFF_DINV;
    int*   rowptr     = (int*)(ws + OFF_ROWPTR);
    int*   base       = (int*)(ws + OFF_BASE);
    int*   gh_t       = (int*)(ws + OFF_GHIST);
    unsigned int* binned = (unsigned int*)(ws + OFF_BINNED);
    float* partial    = ws + OFF_PART;            // aliases binned (dead after agg)
    ushort* u         = (ushort*)(ws + OFF_U);
    unsigned* xd8     = (unsigned*)(ws + OFF_XD8);  // aliases pre (dead by gemm)
    ushort* pre       = (ushort*)(ws + OFF_PRE);
    ushort* Bt        = (ushort*)(ws + OFF_BT);

    k_hist<<<NCHUNK + 64, 256, 0, stream>>>(col, gh_t, W, skipW, Bt);
    k_scan_chunks<<<(NBUCK_P + 3) / 4, 256, 0, stream>>>(gh_t, base);
    k_scan_bases<<<1, 1024, 0, stream>>>(base, rowptr);
    k_scatter_bin<<<NCHUNK, 256, 0, stream>>>(row, col, gh_t, base, binned);
    k_sortbucket<<<NBUCK, 256, 0, stream>>>(binned, base, rowptr, dinv, x, xd8);
    k_agg<<<(N_PAD * 16 + 255) / 256, 256, 0, stream>>>(xd8, dinv, rowptr, binned, u);
    k_gemm<<<NBUCK, 256, 0, stream>>>(u, x, Bt, bias, pre, partial);
    k_reduce<<<128, 256, 0, stream>>>(partial, gamma, beta, scaleshift);
    k_apply<<<(N_NODES * 32 + 255) / 256, 256, 0, stream>>>(pre, out, scaleshift);
}